// Round 1
// baseline (61.995 us; speedup 1.0000x reference)
//
#include <hip/hip_runtime.h>
#include <math.h>

#define DEPTH    11
#define NNODES   4095
#define DIN      768
#define NTOK     8192

// ---------------------------------------------------------------------------
// Transpose w_out [768][4095] -> wT [4095][768] so the main kernel's per-node
// output column becomes a contiguous coalesced row.
// ---------------------------------------------------------------------------
__global__ __launch_bounds__(256) void fff_transpose(const float* __restrict__ src,
                                                     float* __restrict__ dst) {
    __shared__ float tile[32][33];   // +1 pad: no LDS bank conflicts
    const int n0 = blockIdx.x * 32;  // node dim (4095)
    const int j0 = blockIdx.y * 32;  // feature dim (768)
    const int tx = threadIdx.x;      // 0..31
    const int ty = threadIdx.y;      // 0..7

#pragma unroll
    for (int i = 0; i < 32; i += 8) {
        const int j = j0 + ty + i;       // always < 768 (grid exact in y)
        const int n = n0 + tx;
        if (n < NNODES) tile[ty + i][tx] = src[(size_t)j * NNODES + n];
    }
    __syncthreads();
#pragma unroll
    for (int i = 0; i < 32; i += 8) {
        const int n = n0 + ty + i;
        const int j = j0 + tx;
        if (n < NNODES) dst[(size_t)n * DIN + j] = tile[tx][ty + i];
    }
}

// ---------------------------------------------------------------------------
// Main kernel: one 64-lane wave per token. Sequential tree walk over the 12
// path nodes; logit dot accumulated in f64 (exact products) to match the
// reference's sign decisions as closely as possible.
// ---------------------------------------------------------------------------
template <bool TRANSPOSED>
__global__ __launch_bounds__(256) void fff_main(const float* __restrict__ x,
                                                const float* __restrict__ w_in,
                                                const float* __restrict__ w_o,
                                                float* __restrict__ out) {
    const int token = (int)((blockIdx.x * blockDim.x + threadIdx.x) >> 6);
    const int lane  = (int)(threadIdx.x & 63);
    if (token >= NTOK) return;

    // Lane owns float4 chunks lane + 64*k (k = 0..2): 768 = 64 lanes * 3 * 4.
    const float4* xr = reinterpret_cast<const float4*>(x + (size_t)token * DIN);
    float4 xv[3];
#pragma unroll
    for (int k = 0; k < 3; ++k) xv[k] = xr[lane + 64 * k];

    float4 acc[3];
#pragma unroll
    for (int k = 0; k < 3; ++k) acc[k] = make_float4(0.f, 0.f, 0.f, 0.f);

    int cur = 0;
#pragma unroll
    for (int d = 0; d <= DEPTH; ++d) {
        // ---- logit = dot(x_row, w_in[cur]) in f64 (f32*f32 exact in f64) ----
        const float4* wr = reinterpret_cast<const float4*>(w_in + (size_t)cur * DIN);
        double part = 0.0;
#pragma unroll
        for (int k = 0; k < 3; ++k) {
            const float4 w = wr[lane + 64 * k];
            part += (double)xv[k].x * (double)w.x;
            part += (double)xv[k].y * (double)w.y;
            part += (double)xv[k].z * (double)w.z;
            part += (double)xv[k].w * (double)w.w;
        }
#pragma unroll
        for (int off = 32; off >= 1; off >>= 1) part += __shfl_xor(part, off);

        // ---- exact-erf GELU ----
        const float logit = (float)part;
        const float g = 0.5f * logit * (1.0f + erff(logit * 0.7071067811865476f));

        // ---- acc += g * w_out[:, cur] ----
        if (TRANSPOSED) {
            const float4* wo = reinterpret_cast<const float4*>(w_o + (size_t)cur * DIN);
#pragma unroll
            for (int k = 0; k < 3; ++k) {
                const float4 w = wo[lane + 64 * k];
                acc[k].x = fmaf(g, w.x, acc[k].x);
                acc[k].y = fmaf(g, w.y, acc[k].y);
                acc[k].z = fmaf(g, w.z, acc[k].z);
                acc[k].w = fmaf(g, w.w, acc[k].w);
            }
        } else {
#pragma unroll
            for (int k = 0; k < 3; ++k) {
                const int j = (lane + 64 * k) * 4;
                acc[k].x = fmaf(g, w_o[(size_t)(j + 0) * NNODES + cur], acc[k].x);
                acc[k].y = fmaf(g, w_o[(size_t)(j + 1) * NNODES + cur], acc[k].y);
                acc[k].z = fmaf(g, w_o[(size_t)(j + 2) * NNODES + cur], acc[k].z);
                acc[k].w = fmaf(g, w_o[(size_t)(j + 3) * NNODES + cur], acc[k].w);
            }
        }

        // ---- move to child (heap indexing): nxt = 2*cur + 1 + (logit > 0) ----
        if (d < DEPTH) cur = 2 * cur + 1 + (part > 0.0 ? 1 : 0);
    }

    float4* orow = reinterpret_cast<float4*>(out + (size_t)token * DIN);
#pragma unroll
    for (int k = 0; k < 3; ++k) orow[lane + 64 * k] = acc[k];
}

extern "C" void kernel_launch(void* const* d_in, const int* in_sizes, int n_in,
                              void* d_out, int out_size, void* d_ws, size_t ws_size,
                              hipStream_t stream) {
    const float* x     = (const float*)d_in[0];   // [8192, 768]
    const float* w_in  = (const float*)d_in[1];   // [4095, 768]
    const float* w_out = (const float*)d_in[2];   // [768, 4095]
    float*       out   = (float*)d_out;           // [8192, 768]

    const size_t need = (size_t)NNODES * DIN * sizeof(float);  // 12.58 MB
    const dim3 mb(256);
    const dim3 mg(NTOK / 4);  // 4 waves/block, 1 token/wave

    if (ws_size >= need) {
        float* wT = (float*)d_ws;
        dim3 tb(32, 8);
        dim3 tg((NNODES + 31) / 32, DIN / 32);
        hipLaunchKernelGGL(fff_transpose, tg, tb, 0, stream, w_out, wT);
        hipLaunchKernelGGL((fff_main<true>), mg, mb, 0, stream, x, w_in, wT, out);
    } else {
        hipLaunchKernelGGL((fff_main<false>), mg, mb, 0, stream, x, w_in, w_out, out);
    }
}